// Round 4
// baseline (112.036 us; speedup 1.0000x reference)
//
#include <hip/hip_runtime.h>
#include <hip/hip_bf16.h>

// Alpha2Assoc: fused single-pass, float4 (4 px/thread) with bounded-scope
// software pipeline: 8 groups x 4 planes, prefetch next group while computing.
// Live set ~75 VGPR (no spills). dwordx4 stores = 4KB/wave-instruction.

#define NUM_D 32
#define NUM_LAYERS 3
#define ALPHA_MIN 1e-4f

__device__ __forceinline__ void step(float a1, float& pr1, float& pr2, float& pr3,
                                     float& o1, float& o2, float& o3) {
    // layer 0 (occ0 == 1)
    float vis1 = pr1;
    float occ1 = 1.0f - vis1;
    // layer 1
    float a2 = a1 * occ1;
    float vis2 = pr2;
    float occ2 = 1.0f - vis2;
    // layer 2
    float a3 = a2 * occ2;
    float vis3 = pr3;

    o1 = vis1;
    o2 = vis2 * occ1;
    o3 = vis3 * occ2;

    pr1 *= (1.0f - a1);
    pr2 *= (1.0f - a2);
    pr3 *= (1.0f - a3);
}

__global__ __launch_bounds__(256) void alpha2assoc_kernel(
    const float4* __restrict__ in,   // [B, D, 1, H, W] as float4
    float4* __restrict__ out,        // [B, D, 3, H, W] as float4
    int HW4,                         // H*W/4
    int nq)                          // B*H*W/4
{
    int t = blockIdx.x * blockDim.x + threadIdx.x;
    if (t >= nq) return;

    int b = t / HW4;
    int p = t - b * HW4;

    const float4* inb = in + (size_t)b * NUM_D * HW4 + p;
    float4* outb = out + (size_t)b * NUM_D * NUM_LAYERS * HW4 + p;

    float4 pr1 = {1.f, 1.f, 1.f, 1.f};
    float4 pr2 = {1.f, 1.f, 1.f, 1.f};
    float4 pr3 = {1.f, 1.f, 1.f, 1.f};

    float4 buf[4];
#pragma unroll
    for (int i = 0; i < 4; ++i) buf[i] = inb[(size_t)i * HW4];

#pragma unroll 1
    for (int g = 0; g < 8; ++g) {
        float4 cur[4];
#pragma unroll
        for (int i = 0; i < 4; ++i) cur[i] = buf[i];

        if (g < 7) {
#pragma unroll
            for (int i = 0; i < 4; ++i)
                buf[i] = inb[(size_t)((g + 1) * 4 + i) * HW4];
        }

#pragma unroll
        for (int i = 0; i < 4; ++i) {
            int d = g * 4 + i;
            float4 av = cur[i];
            float4 o1, o2, o3;
            step(fmaxf(av.x, ALPHA_MIN), pr1.x, pr2.x, pr3.x, o1.x, o2.x, o3.x);
            step(fmaxf(av.y, ALPHA_MIN), pr1.y, pr2.y, pr3.y, o1.y, o2.y, o3.y);
            step(fmaxf(av.z, ALPHA_MIN), pr1.z, pr2.z, pr3.z, o1.z, o2.z, o3.z);
            step(fmaxf(av.w, ALPHA_MIN), pr1.w, pr2.w, pr3.w, o1.w, o2.w, o3.w);

            float4* ob = &outb[(size_t)d * NUM_LAYERS * HW4];
            ob[0]           = o1;
            ob[HW4]         = o2;
            ob[2 * (size_t)HW4] = o3;
        }
    }
}

extern "C" void kernel_launch(void* const* d_in, const int* in_sizes, int n_in,
                              void* d_out, int out_size, void* d_ws, size_t ws_size,
                              hipStream_t stream) {
    const float* in = (const float*)d_in[0];
    float* out = (float*)d_out;

    const int HW = 512 * 512;
    const int n = in_sizes[0];           // B*D*HW
    const int npix = n / NUM_D;          // B*HW
    const int HW4 = HW / 4;
    const int nq = npix / 4;

    int block = 256;
    int grid = (nq + block - 1) / block;
    alpha2assoc_kernel<<<grid, block, 0, stream>>>(
        (const float4*)in, (float4*)out, HW4, nq);
}

// Round 7
// 82.887 us; speedup vs baseline: 1.3517x; 1.3517x over previous
//
#include <hip/hip_runtime.h>
#include <hip/hip_bf16.h>

// Alpha2Assoc: fused single-pass over D, wave-contiguous store runs.
// Each thread handles G=4 float4-groups strided by 64 lanes, so each WAVE
// covers 4 KB contiguous per plane; per-d outputs staged in registers and
// stored address-ordered -> 4 back-to-back 1KB stores per (d,layer),
// mimicking the 7.0 TB/s fill's per-wave sequential pattern.
// 2-deep input prefetch across d (1 wave/SIMD, reads must self-hide).

#define NUM_D 32
#define NUM_LAYERS 3
#define ALPHA_MIN 1e-4f
#define G 4  // float4 groups per thread, strided by 64 lanes

typedef float f32x4 __attribute__((ext_vector_type(4)));

__device__ __forceinline__ void step4(const f32x4& av, f32x4& pr1, f32x4& pr2,
                                      f32x4& pr3, f32x4& o1, f32x4& o2, f32x4& o3) {
#pragma unroll
    for (int j = 0; j < 4; ++j) {
        float a1 = fmaxf(av[j], ALPHA_MIN);
        float p1 = pr1[j], p2 = pr2[j], p3 = pr3[j];

        // layer 0 (occ0 == 1)
        float vis1 = p1;
        float occ1 = 1.0f - vis1;
        // layer 1
        float a2 = a1 * occ1;
        float vis2 = p2;
        float occ2 = 1.0f - vis2;
        // layer 2
        float a3 = a2 * occ2;
        float vis3 = p3;

        o1[j] = vis1;
        o2[j] = vis2 * occ1;
        o3[j] = vis3 * occ2;

        pr1[j] = p1 * (1.0f - a1);
        pr2[j] = p2 * (1.0f - a2);
        pr3[j] = p3 * (1.0f - a3);
    }
}

// block = 128 threads (2 waves), each thread G=4 float4 groups strided by 64.
// Wave covers 64*G float4 = 4 KB contiguous per plane. Block covers 2048 px.
// Grid = B*HW/4 / (128*G) = 512 blocks (2 per CU).
__global__ __launch_bounds__(128) void alpha2assoc_kernel(
    const f32x4* __restrict__ in,   // [B, D, 1, H, W] as f32x4
    f32x4* __restrict__ out,        // [B, D, 3, H, W] as f32x4
    int HW4)                        // H*W/4
{
    const int wv = threadIdx.x >> 6;        // wave in block (0..1)
    const int lane = threadIdx.x & 63;

    // float4-index of this block's first element (512 float4 per block)
    const int qblk = blockIdx.x * (128 * G);
    const int b = qblk / HW4;               // block never crosses batch (65536 % 512 == 0)
    const int p0 = (qblk - b * HW4) + wv * (64 * G) + lane;  // + i*64, i<G

    const f32x4* inb = in + (size_t)b * NUM_D * HW4 + p0;
    f32x4* outb = out + (size_t)b * NUM_D * NUM_LAYERS * HW4 + p0;

    f32x4 pr1[G], pr2[G], pr3[G];
#pragma unroll
    for (int i = 0; i < G; ++i) {
        pr1[i] = (f32x4){1.f, 1.f, 1.f, 1.f};
        pr2[i] = (f32x4){1.f, 1.f, 1.f, 1.f};
        pr3[i] = (f32x4){1.f, 1.f, 1.f, 1.f};
    }

    // 2-deep prefetch across d
    f32x4 buf0[G], buf1[G];
#pragma unroll
    for (int i = 0; i < G; ++i) buf0[i] = inb[(size_t)0 * HW4 + i * 64];
#pragma unroll
    for (int i = 0; i < G; ++i) buf1[i] = inb[(size_t)1 * HW4 + i * 64];

#pragma unroll 1
    for (int d = 0; d < NUM_D; ++d) {
        f32x4 cur[G];
#pragma unroll
        for (int i = 0; i < G; ++i) cur[i] = buf0[i];
#pragma unroll
        for (int i = 0; i < G; ++i) buf0[i] = buf1[i];
        if (d + 2 < NUM_D) {
#pragma unroll
            for (int i = 0; i < G; ++i) buf1[i] = inb[(size_t)(d + 2) * HW4 + i * 64];
        }

        f32x4 o1[G], o2[G], o3[G];
#pragma unroll
        for (int i = 0; i < G; ++i)
            step4(cur[i], pr1[i], pr2[i], pr3[i], o1[i], o2[i], o3[i]);

        // address-ordered stores: for each layer, 4 consecutive 1KB wave-stores
        f32x4* ob = &outb[(size_t)d * NUM_LAYERS * HW4];
#pragma unroll
        for (int i = 0; i < G; ++i) __builtin_nontemporal_store(o1[i], &ob[i * 64]);
#pragma unroll
        for (int i = 0; i < G; ++i) __builtin_nontemporal_store(o2[i], &ob[(size_t)HW4 + i * 64]);
#pragma unroll
        for (int i = 0; i < G; ++i) __builtin_nontemporal_store(o3[i], &ob[2 * (size_t)HW4 + i * 64]);
    }
}

extern "C" void kernel_launch(void* const* d_in, const int* in_sizes, int n_in,
                              void* d_out, int out_size, void* d_ws, size_t ws_size,
                              hipStream_t stream) {
    const float* in = (const float*)d_in[0];
    float* out = (float*)d_out;

    const int HW = 512 * 512;
    const int n = in_sizes[0];           // B*D*HW
    const int npix = n / NUM_D;          // B*HW
    const int nq = npix / 4;             // float4 groups total

    int block = 128;
    int grid = nq / (block * G);         // 512 blocks, exact division
    alpha2assoc_kernel<<<grid, block, 0, stream>>>(
        (const f32x4*)in, (f32x4*)out, HW / 4);
}